// Round 8
// baseline (275.612 us; speedup 1.0000x reference)
//
#include <hip/hip_runtime.h>
#include <hip/hip_bf16.h>

#define NB 2
#define NS 2048
#define ND 1024
#define NH 16
#define NDK 64
#define GK 1024  // GEMM K (= ND)

using bf16_t = __hip_bfloat16;
typedef __attribute__((ext_vector_type(8))) short bf16x8;
typedef __attribute__((ext_vector_type(4))) float f32x4;
typedef unsigned short u16;
typedef unsigned int u32;

#define SC_LOG2E 0.1803368801f  // 0.125 * log2(e)

static __device__ __forceinline__ u16 f2bf(float f) {
    __hip_bfloat16 h = __float2bfloat16(f);
    return *reinterpret_cast<u16*>(&h);
}

// packed f32x2 -> bf16x2 (RNE), single instruction
static __device__ __forceinline__ u32 cvtpk2(float a, float b) {
    u32 r;
    asm("v_cvt_pk_bf16_f32 %0, %1, %2" : "=v"(r) : "v"(a), "v"(b));
    return r;
}

// async global->LDS DMA, 16B per lane. LDS dest = wave-uniform base + lane*16.
#define GLDS16(gp, lp)                                                                    \
    __builtin_amdgcn_global_load_lds((const __attribute__((address_space(1))) void*)(gp), \
                                     (__attribute__((address_space(3))) void*)(lp), 16, 0, 0)

// ---------------------------------------------------------------------------
// Kernel 0: fused prep — grid (4096, 5):
//   y=0..2 : q/k/v fp32 -> bf16
//   y=3    : Wq/Wk/Wv/Wo fp32 -> bf16 (x>>10 selects weight)
//   y=4    : combined mask  comb = (am==1) ? -1 : SC_LOG2E*(1 + 0.5*cm)
// ---------------------------------------------------------------------------
struct PrepArgs {
    const float* qkv_s[3];
    u16* qkv_d[3];
    const float* w_s[4];
    u16* w_d[4];
    const int* am;
    const float* cm;
    float* comb;
};

__global__ __launch_bounds__(256) void prep_kernel(PrepArgs a) {
    const int x = blockIdx.x, y = blockIdx.y, tid = threadIdx.x;
    if (y < 3) {
        int i = x * 256 + tid;
        float4 v = reinterpret_cast<const float4*>(a.qkv_s[y])[i];
        ushort4 o;
        o.x = f2bf(v.x); o.y = f2bf(v.y); o.z = f2bf(v.z); o.w = f2bf(v.w);
        reinterpret_cast<ushort4*>(a.qkv_d[y])[i] = o;
    } else if (y == 3) {
        int w = x >> 10;
        int i = (x & 1023) * 256 + tid;
        float4 v = reinterpret_cast<const float4*>(a.w_s[w])[i];
        ushort4 o;
        o.x = f2bf(v.x); o.y = f2bf(v.y); o.z = f2bf(v.z); o.w = f2bf(v.w);
        reinterpret_cast<ushort4*>(a.w_d[w])[i] = o;
    } else {
        int i = (x * 256 + tid) * 4;
        int4 m = *reinterpret_cast<const int4*>(a.am + i);
        float4 c = *reinterpret_cast<const float4*>(a.cm + i);
        float4 r;
        r.x = (m.x == 1) ? -1.0f : fmaf(0.5f * SC_LOG2E, c.x, SC_LOG2E);
        r.y = (m.y == 1) ? -1.0f : fmaf(0.5f * SC_LOG2E, c.y, SC_LOG2E);
        r.z = (m.z == 1) ? -1.0f : fmaf(0.5f * SC_LOG2E, c.z, SC_LOG2E);
        r.w = (m.w == 1) ? -1.0f : fmaf(0.5f * SC_LOG2E, c.w, SC_LOG2E);
        *reinterpret_cast<float4*>(a.comb + i) = r;
    }
}

// ---------------------------------------------------------------------------
// Kernel 2: m97-style bf16 MFMA GEMM with global_load_lds staging.
// C[m][n] = sum_k A[m][k]*B[n][k] + bias[n].  BM=128, BK=32, dbuf LDS.
// mode 0: fp32 [M][ND] out.  mode 1: bf16 [B,H,S,DK].  mode 2: bf16 [B,H,DK,S]
// (transposed, packed 8B stores — replaces the separate vtrans kernel).
// blockIdx.z selects one of 3 argument sets (QKV fused launch).
// ---------------------------------------------------------------------------
struct MMArgs {
    const u16* A;
    const u16* W;
    const float* bias;
    void* out;
    int mode;
};

template <int BN>
__global__ __launch_bounds__(256) void mm_glds(MMArgs g0, MMArgs g1, MMArgs g2) {
    const MMArgs ga = (blockIdx.z == 0) ? g0 : (blockIdx.z == 1) ? g1 : g2;
    constexpr int BM = 128, BK = 32;
    constexpr int JN = BN / 32;
    __shared__ __align__(16) u16 As[2][BM * BK];
    __shared__ __align__(16) u16 Bs[2][BN * BK];

    const int tid = threadIdx.x;
    const int lane = tid & 63;
    const int w = tid >> 6;
    const int wm = w >> 1, wn = w & 1;
    const int fr = lane & 15, fg = lane >> 4;
    const int bm0 = blockIdx.y * BM, bn0 = blockIdx.x * BN;

    const u16* agp = ga.A + (size_t)(bm0 + w * 32 + (lane >> 2)) * GK + (lane & 3) * 8;
    const u16* bgp = ga.W +
                     (size_t)(bn0 + w * (BN == 128 ? 32 : 16) + (lane >> 2)) * GK +
                     (lane & 3) * 8;

    f32x4 acc[4][JN];
    const f32x4 z4 = {0.f, 0.f, 0.f, 0.f};
#pragma unroll
    for (int i = 0; i < 4; ++i)
#pragma unroll
        for (int j = 0; j < JN; ++j) acc[i][j] = z4;

    {
        u16* la = &As[0][w * 1024];
        u16* lb = &Bs[0][w * (BN == 128 ? 1024 : 512)];
        GLDS16(agp, la);
        GLDS16(agp + 16 * GK, la + 512);
        if (BN == 128) {
            GLDS16(bgp, lb);
            GLDS16(bgp + 16 * GK, lb + 512);
        } else {
            GLDS16(bgp, lb);
        }
    }
    __syncthreads();

    int cur = 0;
    for (int kt = 0; kt < GK / BK; ++kt) {
        if (kt + 1 < GK / BK) {
            const int ko = (kt + 1) * BK;
            u16* la = &As[cur ^ 1][w * 1024];
            u16* lb = &Bs[cur ^ 1][w * (BN == 128 ? 1024 : 512)];
            GLDS16(agp + ko, la);
            GLDS16(agp + ko + 16 * GK, la + 512);
            if (BN == 128) {
                GLDS16(bgp + ko, lb);
                GLDS16(bgp + ko + 16 * GK, lb + 512);
            } else {
                GLDS16(bgp + ko, lb);
            }
        }
        bf16x8 af[4], bfr[JN];
#pragma unroll
        for (int i = 0; i < 4; ++i)
            af[i] = *(const bf16x8*)&As[cur][(wm * 64 + i * 16 + fr) * BK + fg * 8];
#pragma unroll
        for (int j = 0; j < JN; ++j)
            bfr[j] = *(const bf16x8*)&Bs[cur][(wn * (BN / 2) + j * 16 + fr) * BK + fg * 8];
#pragma unroll
        for (int i = 0; i < 4; ++i)
#pragma unroll
            for (int j = 0; j < JN; ++j)
                acc[i][j] = __builtin_amdgcn_mfma_f32_16x16x32_bf16(af[i], bfr[j], acc[i][j],
                                                                    0, 0, 0);
        __syncthreads();
        cur ^= 1;
    }

#pragma unroll
    for (int j = 0; j < JN; ++j) {
        const int col = bn0 + wn * (BN / 2) + j * 16 + fr;
        const float bv_ = ga.bias[col];
        if (ga.mode == 2) {
            // transposed bf16 out [B,H,DK,S], 4 consecutive s packed per store
            const int h_ = col >> 6, dk = col & (NDK - 1);
#pragma unroll
            for (int i = 0; i < 4; ++i) {
                const int row0 = bm0 + wm * 64 + i * 16 + fg * 4;
                const int b_ = row0 >> 11, s_ = row0 & (NS - 1);
                uint2 pw;
                pw.x = cvtpk2(acc[i][j][0] + bv_, acc[i][j][1] + bv_);
                pw.y = cvtpk2(acc[i][j][2] + bv_, acc[i][j][3] + bv_);
                *(uint2*)((u16*)ga.out +
                          (((size_t)(b_ * NH + h_)) * NDK + dk) * NS + s_) = pw;
            }
        } else {
#pragma unroll
            for (int i = 0; i < 4; ++i) {
#pragma unroll
                for (int r = 0; r < 4; ++r) {
                    const int row = bm0 + wm * 64 + i * 16 + fg * 4 + r;
                    const float val = acc[i][j][r] + bv_;
                    if (ga.mode == 1) {
                        const int b_ = row >> 11, s_ = row & (NS - 1);
                        const int h_ = col >> 6, dk = col & (NDK - 1);
                        ((bf16_t*)ga.out)[(((size_t)(b_ * NH + h_)) * NS + s_) * NDK + dk] =
                            __float2bfloat16(val);
                    } else {
                        ((float*)ga.out)[(size_t)row * ND + col] = val;
                    }
                }
            }
        }
    }
}

// ---------------------------------------------------------------------------
// Kernel 3: MFMA flash attention. K DMA-staged in LDS (dbuf, XOR-swizzled
// source + same XOR on read); V^T fragments read DIRECTLY from global (they
// are identical across the 4 waves and L1/L2-resident — staging V in LDS was
// pure occupancy loss). Pt per-warp XOR-swizzled linear. LDS = 24576 B.
// No-max softmax (logits bounded); lsum via ones-MFMA; cvt_pk P-pack.
// Block = 64 q-rows of one (b,h); 4 warps x 16 q. 32 key-tiles of 64.
// Swapped QK^T: mfma(K,Q) -> S^T (q = lane&15, key = (lane>>4)*4+reg).
// ---------------------------------------------------------------------------
__global__ __launch_bounds__(256, 5) void flash_mfma(const u16* __restrict__ Qh,
                                                     const u16* __restrict__ Kh,
                                                     const u16* __restrict__ VhT,
                                                     const float* __restrict__ comb,
                                                     float* __restrict__ attnOut,
                                                     u16* __restrict__ concatOut) {
    __shared__ __align__(16) u16 Kt[2][64 * 64];  // [key][dk], cols XOR-swizzled
    __shared__ __align__(16) u16 Pt[4][16][64];   // per-warp [q][key], XOR-swizzled

    const int tid = threadIdx.x;
    const int w = tid >> 6;
    const int lane = tid & 63;
    const int qc = lane & 15;
    const int g = lane >> 4;
    const int bh = blockIdx.y;
    const int b_ = bh >> 4, h_ = bh & 15;
    const int qw = blockIdx.x * 64 + w * 16;

    const size_t bhoff = (size_t)bh * NS * NDK;

    // ---- K staging addresses (wave w stages rows w*16..w*16+15) ----
    const int srow = lane >> 3;          // 0..7 within 8-row chunk
    const int sblk = (lane & 7) ^ srow;  // swizzled 16B block (involution)
    const u16* kgp = Kh + bhoff + (size_t)(w * 16 + srow) * NDK + sblk * 8;

    // ---- V^T global fragment base: row (dsub*16+qc), col kt + kc*32 + g*8 ----
    const u16* vbase = VhT + bhoff + (size_t)qc * NS + g * 8;

    // ---- Q fragments in registers for whole kernel ----
    bf16x8 qf[2];
    {
        const u16* qp = Qh + bhoff + (size_t)(qw + qc) * NDK + g * 8;
        qf[0] = *(const bf16x8*)(qp);
        qf[1] = *(const bf16x8*)(qp + 32);
    }

    // ones operand for the row-sum MFMA (bf16 1.0 = 0x3F80)
    bf16x8 vones;
#pragma unroll
    for (int j = 0; j < 8; ++j) vones[j] = (short)0x3F80;

    const f32x4 z4 = {0.f, 0.f, 0.f, 0.f};
    f32x4 o[4];
    o[0] = o[1] = o[2] = o[3] = z4;
    f32x4 o_l = z4;  // row-sums of P (softmax denominator), same layout as o rows

    const float* crow = comb + (size_t)(qw + qc) * NS;
    const int kxor = qc & 7;         // K read swizzle (16B-block units)
    const int pxor = (qc & 7) << 4;  // Pt swizzle (bytes)
    char* ptrow = (char*)&Pt[w][0][0] + qc * 128;

    // prologue: stage K tile 0 into buf 0
    GLDS16(kgp, &Kt[0][(w * 16) * 64]);
    GLDS16(kgp + 8 * NDK, &Kt[0][(w * 16) * 64 + 512]);
    __syncthreads();

    int cur = 0;
    for (int kt = 0; kt < NS; kt += 64) {
        // stage next K tile into the other buffer (overlaps with compute)
        if (kt + 64 < NS) {
            u16* kd = &Kt[cur ^ 1][(w * 16) * 64];
            GLDS16(kgp + (kt + 64) * NDK, kd);
            GLDS16(kgp + (kt + 64 + 8) * NDK, kd + 512);
        }

        // ---- V fragment loads for THIS tile (global; covered by QK + exp) ----
        bf16x8 vf[2][4];
#pragma unroll
        for (int kc = 0; kc < 2; ++kc)
#pragma unroll
            for (int dsub = 0; dsub < 4; ++dsub)
                vf[kc][dsub] =
                    *(const bf16x8*)(vbase + (size_t)dsub * 16 * NS + kt + kc * 32);

        // ---- QK^T -> S^T [64 key][16 q] ----
        f32x4 s[4];
        s[0] = s[1] = s[2] = s[3] = z4;
#pragma unroll
        for (int kc = 0; kc < 2; ++kc) {
#pragma unroll
            for (int ks = 0; ks < 4; ++ks) {
                bf16x8 kf = *(const bf16x8*)&Kt[cur][(ks * 16 + qc) * 64 +
                                                     (((kc << 2) | g) ^ kxor) * 8];
                s[ks] = __builtin_amdgcn_mfma_f32_16x16x32_bf16(kf, qf[kc], s[ks], 0, 0, 0);
            }
        }

        // ---- no-max softmax: p = exp2(s_raw * comb'), masked -> 0 ----
#pragma unroll
        for (int ks = 0; ks < 4; ++ks) {
            float4 c4 = *(const float4*)(crow + kt + ks * 16 + g * 4);
            const float* cc = (const float*)&c4;
            float p0 = __builtin_amdgcn_exp2f(s[ks][0] * cc[0]);
            float p1 = __builtin_amdgcn_exp2f(s[ks][1] * cc[1]);
            float p2 = __builtin_amdgcn_exp2f(s[ks][2] * cc[2]);
            float p3 = __builtin_amdgcn_exp2f(s[ks][3] * cc[3]);
            p0 = (cc[0] < 0.f) ? 0.f : p0;
            p1 = (cc[1] < 0.f) ? 0.f : p1;
            p2 = (cc[2] < 0.f) ? 0.f : p2;
            p3 = (cc[3] < 0.f) ? 0.f : p3;
            uint2 pw;
            pw.x = cvtpk2(p0, p1);
            pw.y = cvtpk2(p2, p3);
            *(uint2*)(ptrow + ((ks * 32 + g * 8) ^ pxor)) = pw;
        }

        // ---- PV: O[q][d] += P[q][key] * V^T[d][key];  o_l += P row-sums ----
#pragma unroll
        for (int kc = 0; kc < 2; ++kc) {
            bf16x8 pf = *(const bf16x8*)(ptrow + ((kc * 64 + g * 16) ^ pxor));
            o_l = __builtin_amdgcn_mfma_f32_16x16x32_bf16(pf, vones, o_l, 0, 0, 0);
#pragma unroll
            for (int dsub = 0; dsub < 4; ++dsub)
                o[dsub] =
                    __builtin_amdgcn_mfma_f32_16x16x32_bf16(pf, vf[kc][dsub], o[dsub], 0, 0, 0);
        }
        __syncthreads();  // drains K DMA + protects buffer swap
        cur ^= 1;
    }

    // ---- normalize + store (attn fp32 [B,H,S,DK], concat bf16 [B,S,D]) ----
    float inv[4];
#pragma unroll
    for (int r = 0; r < 4; ++r) inv[r] = 1.0f / o_l[r];

#pragma unroll
    for (int dsub = 0; dsub < 4; ++dsub) {
#pragma unroll
        for (int r = 0; r < 4; ++r) {
            const float val = o[dsub][r] * inv[r];
            const int qg = qw + g * 4 + r;
            const int d = dsub * 16 + qc;
            attnOut[bhoff + (size_t)qg * NDK + d] = val;
            concatOut[((size_t)b_ * NS + qg) * ND + h_ * NDK + d] = f2bf(val);
        }
    }
}

// ---------------------------------------------------------------------------
extern "C" void kernel_launch(void* const* d_in, const int* in_sizes, int n_in,
                              void* d_out, int out_size, void* d_ws, size_t ws_size,
                              hipStream_t stream) {
    const float* q = (const float*)d_in[0];
    const float* k = (const float*)d_in[1];
    const float* v = (const float*)d_in[2];
    const int* am = (const int*)d_in[3];
    const float* cm = (const float*)d_in[4];
    const float* Wq = (const float*)d_in[5];
    const float* bq = (const float*)d_in[6];
    const float* Wk = (const float*)d_in[7];
    const float* bk = (const float*)d_in[8];
    const float* Wv = (const float*)d_in[9];
    const float* bv = (const float*)d_in[10];
    const float* Wo = (const float*)d_in[11];
    const float* bo = (const float*)d_in[12];

    float* out = (float*)d_out;                    // [B,S,D] fp32
    float* attn_out = out + (size_t)NB * NS * ND;  // [B,H,S,DK] fp32

    char* p = (char*)d_ws;
    float* CB = (float*)p;  p += (size_t)NS * NS * 4;
    u16* qb = (u16*)p;      p += (size_t)NB * NS * ND * 2;
    u16* kb_ = (u16*)p;     p += (size_t)NB * NS * ND * 2;
    u16* vb_ = (u16*)p;     p += (size_t)NB * NS * ND * 2;
    u16* Wqb = (u16*)p;     p += (size_t)ND * ND * 2;
    u16* Wkb = (u16*)p;     p += (size_t)ND * ND * 2;
    u16* Wvb = (u16*)p;     p += (size_t)ND * ND * 2;
    u16* Wob = (u16*)p;     p += (size_t)ND * ND * 2;
    u16* Qh = (u16*)p;      p += (size_t)NB * NS * ND * 2;
    u16* Kh = (u16*)p;      p += (size_t)NB * NS * ND * 2;
    u16* VhT = (u16*)p;     p += (size_t)NB * NS * ND * 2;
    u16* CCb = (u16*)p;     p += (size_t)NB * NS * ND * 2;

    PrepArgs pa;
    pa.qkv_s[0] = q;  pa.qkv_d[0] = qb;
    pa.qkv_s[1] = k;  pa.qkv_d[1] = kb_;
    pa.qkv_s[2] = v;  pa.qkv_d[2] = vb_;
    pa.w_s[0] = Wq;   pa.w_d[0] = Wqb;
    pa.w_s[1] = Wk;   pa.w_d[1] = Wkb;
    pa.w_s[2] = Wv;   pa.w_d[2] = Wvb;
    pa.w_s[3] = Wo;   pa.w_d[3] = Wob;
    pa.am = am;
    pa.cm = cm;
    pa.comb = CB;
    hipLaunchKernelGGL(prep_kernel, dim3(4096, 5), dim3(256), 0, stream, pa);

    MMArgs mq = {qb, Wqb, bq, (void*)Qh, 1};
    MMArgs mk = {kb_, Wkb, bk, (void*)Kh, 1};
    MMArgs mv = {vb_, Wvb, bv, (void*)VhT, 2};
    hipLaunchKernelGGL((mm_glds<128>), dim3(ND / 128, 4096 / 128, 3), dim3(256), 0, stream,
                       mq, mk, mv);

    hipLaunchKernelGGL(flash_mfma, dim3(NS / 64, NB * NH), dim3(256), 0, stream, Qh, Kh, VhT,
                       CB, attn_out, CCb);

    MMArgs mo = {CCb, Wob, bo, (void*)out, 0};
    hipLaunchKernelGGL((mm_glds<64>), dim3(ND / 64, 4096 / 128, 1), dim3(256), 0, stream,
                       mo, mo, mo);
}

// Round 9
// 171.093 us; speedup vs baseline: 1.6109x; 1.6109x over previous
//
#include <hip/hip_runtime.h>
#include <hip/hip_bf16.h>

#define NB 2
#define NS 2048
#define ND 1024
#define NH 16
#define NDK 64
#define GK 1024  // GEMM K (= ND)

using bf16_t = __hip_bfloat16;
typedef __attribute__((ext_vector_type(8))) short bf16x8;
typedef __attribute__((ext_vector_type(4))) float f32x4;
typedef unsigned short u16;
typedef unsigned int u32;

#define SC_LOG2E 0.1803368801f  // 0.125 * log2(e)

static __device__ __forceinline__ u16 f2bf(float f) {
    __hip_bfloat16 h = __float2bfloat16(f);
    return *reinterpret_cast<u16*>(&h);
}

// packed f32x2 -> bf16x2 (RNE), single instruction
static __device__ __forceinline__ u32 cvtpk2(float a, float b) {
    u32 r;
    asm("v_cvt_pk_bf16_f32 %0, %1, %2" : "=v"(r) : "v"(a), "v"(b));
    return r;
}

// async global->LDS DMA, 16B per lane. LDS dest = wave-uniform base + lane*16.
#define GLDS16(gp, lp)                                                                    \
    __builtin_amdgcn_global_load_lds((const __attribute__((address_space(1))) void*)(gp), \
                                     (__attribute__((address_space(3))) void*)(lp), 16, 0, 0)

// ---------------------------------------------------------------------------
// Kernel 0: fused prep — grid (4096, 5):
//   y=0..2 : q/k/v fp32 -> bf16
//   y=3    : Wq/Wk/Wv/Wo fp32 -> bf16 (x>>10 selects weight)
//   y=4    : combined mask  comb = (am==1) ? -1 : SC_LOG2E*(1 + 0.5*cm)
// ---------------------------------------------------------------------------
struct PrepArgs {
    const float* qkv_s[3];
    u16* qkv_d[3];
    const float* w_s[4];
    u16* w_d[4];
    const int* am;
    const float* cm;
    float* comb;
};

__global__ __launch_bounds__(256) void prep_kernel(PrepArgs a) {
    const int x = blockIdx.x, y = blockIdx.y, tid = threadIdx.x;
    if (y < 3) {
        int i = x * 256 + tid;
        float4 v = reinterpret_cast<const float4*>(a.qkv_s[y])[i];
        ushort4 o;
        o.x = f2bf(v.x); o.y = f2bf(v.y); o.z = f2bf(v.z); o.w = f2bf(v.w);
        reinterpret_cast<ushort4*>(a.qkv_d[y])[i] = o;
    } else if (y == 3) {
        int w = x >> 10;
        int i = (x & 1023) * 256 + tid;
        float4 v = reinterpret_cast<const float4*>(a.w_s[w])[i];
        ushort4 o;
        o.x = f2bf(v.x); o.y = f2bf(v.y); o.z = f2bf(v.z); o.w = f2bf(v.w);
        reinterpret_cast<ushort4*>(a.w_d[w])[i] = o;
    } else {
        int i = (x * 256 + tid) * 4;
        int4 m = *reinterpret_cast<const int4*>(a.am + i);
        float4 c = *reinterpret_cast<const float4*>(a.cm + i);
        float4 r;
        r.x = (m.x == 1) ? -1.0f : fmaf(0.5f * SC_LOG2E, c.x, SC_LOG2E);
        r.y = (m.y == 1) ? -1.0f : fmaf(0.5f * SC_LOG2E, c.y, SC_LOG2E);
        r.z = (m.z == 1) ? -1.0f : fmaf(0.5f * SC_LOG2E, c.z, SC_LOG2E);
        r.w = (m.w == 1) ? -1.0f : fmaf(0.5f * SC_LOG2E, c.w, SC_LOG2E);
        *reinterpret_cast<float4*>(a.comb + i) = r;
    }
}

// ---------------------------------------------------------------------------
// Kernel 2: m97-style bf16 MFMA GEMM with global_load_lds staging.
// C[m][n] = sum_k A[m][k]*B[n][k] + bias[n].  BM=128, BK=32, dbuf LDS.
// mode 0: fp32 [M][ND] out.  mode 1: bf16 [B,H,S,DK].  mode 2: bf16 [B,H,DK,S]
// (transposed, packed 8B stores — V^T produced directly, no vtrans kernel).
// blockIdx.z selects one of 3 argument sets (QKV fused launch).
// ---------------------------------------------------------------------------
struct MMArgs {
    const u16* A;
    const u16* W;
    const float* bias;
    void* out;
    int mode;
};

template <int BN>
__global__ __launch_bounds__(256) void mm_glds(MMArgs g0, MMArgs g1, MMArgs g2) {
    const MMArgs ga = (blockIdx.z == 0) ? g0 : (blockIdx.z == 1) ? g1 : g2;
    constexpr int BM = 128, BK = 32;
    constexpr int JN = BN / 32;
    __shared__ __align__(16) u16 As[2][BM * BK];
    __shared__ __align__(16) u16 Bs[2][BN * BK];

    const int tid = threadIdx.x;
    const int lane = tid & 63;
    const int w = tid >> 6;
    const int wm = w >> 1, wn = w & 1;
    const int fr = lane & 15, fg = lane >> 4;
    const int bm0 = blockIdx.y * BM, bn0 = blockIdx.x * BN;

    const u16* agp = ga.A + (size_t)(bm0 + w * 32 + (lane >> 2)) * GK + (lane & 3) * 8;
    const u16* bgp = ga.W +
                     (size_t)(bn0 + w * (BN == 128 ? 32 : 16) + (lane >> 2)) * GK +
                     (lane & 3) * 8;

    f32x4 acc[4][JN];
    const f32x4 z4 = {0.f, 0.f, 0.f, 0.f};
#pragma unroll
    for (int i = 0; i < 4; ++i)
#pragma unroll
        for (int j = 0; j < JN; ++j) acc[i][j] = z4;

    {
        u16* la = &As[0][w * 1024];
        u16* lb = &Bs[0][w * (BN == 128 ? 1024 : 512)];
        GLDS16(agp, la);
        GLDS16(agp + 16 * GK, la + 512);
        if (BN == 128) {
            GLDS16(bgp, lb);
            GLDS16(bgp + 16 * GK, lb + 512);
        } else {
            GLDS16(bgp, lb);
        }
    }
    __syncthreads();

    int cur = 0;
    for (int kt = 0; kt < GK / BK; ++kt) {
        if (kt + 1 < GK / BK) {
            const int ko = (kt + 1) * BK;
            u16* la = &As[cur ^ 1][w * 1024];
            u16* lb = &Bs[cur ^ 1][w * (BN == 128 ? 1024 : 512)];
            GLDS16(agp + ko, la);
            GLDS16(agp + ko + 16 * GK, la + 512);
            if (BN == 128) {
                GLDS16(bgp + ko, lb);
                GLDS16(bgp + ko + 16 * GK, lb + 512);
            } else {
                GLDS16(bgp + ko, lb);
            }
        }
        bf16x8 af[4], bfr[JN];
#pragma unroll
        for (int i = 0; i < 4; ++i)
            af[i] = *(const bf16x8*)&As[cur][(wm * 64 + i * 16 + fr) * BK + fg * 8];
#pragma unroll
        for (int j = 0; j < JN; ++j)
            bfr[j] = *(const bf16x8*)&Bs[cur][(wn * (BN / 2) + j * 16 + fr) * BK + fg * 8];
#pragma unroll
        for (int i = 0; i < 4; ++i)
#pragma unroll
            for (int j = 0; j < JN; ++j)
                acc[i][j] = __builtin_amdgcn_mfma_f32_16x16x32_bf16(af[i], bfr[j], acc[i][j],
                                                                    0, 0, 0);
        __syncthreads();
        cur ^= 1;
    }

#pragma unroll
    for (int j = 0; j < JN; ++j) {
        const int col = bn0 + wn * (BN / 2) + j * 16 + fr;
        const float bv_ = ga.bias[col];
        if (ga.mode == 2) {
            // transposed bf16 out [B,H,DK,S], 4 consecutive s packed per store
            const int h_ = col >> 6, dk = col & (NDK - 1);
#pragma unroll
            for (int i = 0; i < 4; ++i) {
                const int row0 = bm0 + wm * 64 + i * 16 + fg * 4;
                const int b_ = row0 >> 11, s_ = row0 & (NS - 1);
                uint2 pw;
                pw.x = cvtpk2(acc[i][j][0] + bv_, acc[i][j][1] + bv_);
                pw.y = cvtpk2(acc[i][j][2] + bv_, acc[i][j][3] + bv_);
                *(uint2*)((u16*)ga.out +
                          (((size_t)(b_ * NH + h_)) * NDK + dk) * NS + s_) = pw;
            }
        } else {
#pragma unroll
            for (int i = 0; i < 4; ++i) {
#pragma unroll
                for (int r = 0; r < 4; ++r) {
                    const int row = bm0 + wm * 64 + i * 16 + fg * 4 + r;
                    const float val = acc[i][j][r] + bv_;
                    if (ga.mode == 1) {
                        const int b_ = row >> 11, s_ = row & (NS - 1);
                        const int h_ = col >> 6, dk = col & (NDK - 1);
                        ((bf16_t*)ga.out)[(((size_t)(b_ * NH + h_)) * NS + s_) * NDK + dk] =
                            __float2bfloat16(val);
                    } else {
                        ((float*)ga.out)[(size_t)row * ND + col] = val;
                    }
                }
            }
        }
    }
}

// ---------------------------------------------------------------------------
// Kernel 3: MFMA flash attention — round-6 structure (proven 103.7 us):
// K and V^T DMA-staged dbuf in LDS (XOR-swizzled source + same XOR on read);
// Pt per-warp XOR-swizzled linear (LDS total 40960 B = 4 blocks/CU).
// Plus verified wins: no-max softmax (exp2 builtin), cvt_pk P-pack, row-sum
// via ones-MFMA (no lsum adds / no end shuffles).
// Block = 64 q-rows of one (b,h); 4 warps x 16 q. 32 key-tiles of 64.
// Swapped QK^T: mfma(K,Q) -> S^T (q = lane&15, key = (lane>>4)*4+reg).
// ---------------------------------------------------------------------------
__global__ __launch_bounds__(256) void flash_mfma(const u16* __restrict__ Qh,
                                                  const u16* __restrict__ Kh,
                                                  const u16* __restrict__ VhT,
                                                  const float* __restrict__ comb,
                                                  float* __restrict__ attnOut,
                                                  u16* __restrict__ concatOut) {
    __shared__ __align__(16) u16 Kt[2][64 * 64];  // [key][dk], cols XOR-swizzled
    __shared__ __align__(16) u16 Vt[2][64 * 64];  // [dk][key], cols XOR-swizzled
    __shared__ __align__(16) u16 Pt[4][16][64];   // per-warp [q][key], XOR-swizzled

    const int tid = threadIdx.x;
    const int w = tid >> 6;
    const int lane = tid & 63;
    const int qc = lane & 15;
    const int g = lane >> 4;
    const int bh = blockIdx.y;
    const int b_ = bh >> 4, h_ = bh & 15;
    const int qw = blockIdx.x * 64 + w * 16;

    const size_t bhoff = (size_t)bh * NS * NDK;

    // ---- staging addresses (wave w stages rows w*16..w*16+15 of K and V^T) ----
    const int srow = lane >> 3;          // 0..7 within 8-row chunk
    const int sblk = (lane & 7) ^ srow;  // swizzled 16B block (involution)
    const u16* kgp = Kh + bhoff + (size_t)(w * 16 + srow) * NDK + sblk * 8;
    const u16* vgp = VhT + bhoff + (size_t)(w * 16 + srow) * NS + sblk * 8;

    // ---- Q fragments in registers for whole kernel ----
    bf16x8 qf[2];
    {
        const u16* qp = Qh + bhoff + (size_t)(qw + qc) * NDK + g * 8;
        qf[0] = *(const bf16x8*)(qp);
        qf[1] = *(const bf16x8*)(qp + 32);
    }

    // ones operand for the row-sum MFMA (bf16 1.0 = 0x3F80)
    bf16x8 vones;
#pragma unroll
    for (int j = 0; j < 8; ++j) vones[j] = (short)0x3F80;

    const f32x4 z4 = {0.f, 0.f, 0.f, 0.f};
    f32x4 o[4];
    o[0] = o[1] = o[2] = o[3] = z4;
    f32x4 o_l = z4;  // row-sums of P (softmax denominator), same layout as o rows

    const float* crow = comb + (size_t)(qw + qc) * NS;
    const int kxor = qc & 7;         // K/V read swizzle (16B-block units)
    const int pxor = (qc & 7) << 4;  // Pt swizzle (bytes)
    char* ptrow = (char*)&Pt[w][0][0] + qc * 128;

    // prologue: stage tile 0 into buf 0
    {
        u16* kd = &Kt[0][(w * 16) * 64];
        u16* vd = &Vt[0][(w * 16) * 64];
        GLDS16(kgp, kd);
        GLDS16(kgp + 8 * NDK, kd + 512);
        GLDS16(vgp, vd);
        GLDS16(vgp + 8 * NS, vd + 512);
    }
    __syncthreads();

    int cur = 0;
    for (int kt = 0; kt < NS; kt += 64) {
        // stage next tile into the other buffer (overlaps with compute)
        if (kt + 64 < NS) {
            u16* kd = &Kt[cur ^ 1][(w * 16) * 64];
            u16* vd = &Vt[cur ^ 1][(w * 16) * 64];
            GLDS16(kgp + (kt + 64) * NDK, kd);
            GLDS16(kgp + (kt + 64 + 8) * NDK, kd + 512);
            GLDS16(vgp + (kt + 64), vd);
            GLDS16(vgp + 8 * NS + (kt + 64), vd + 512);
        }

        // ---- QK^T -> S^T [64 key][16 q] ----
        f32x4 s[4];
        s[0] = s[1] = s[2] = s[3] = z4;
#pragma unroll
        for (int kc = 0; kc < 2; ++kc) {
#pragma unroll
            for (int ks = 0; ks < 4; ++ks) {
                bf16x8 kf = *(const bf16x8*)&Kt[cur][(ks * 16 + qc) * 64 +
                                                     (((kc << 2) | g) ^ kxor) * 8];
                s[ks] = __builtin_amdgcn_mfma_f32_16x16x32_bf16(kf, qf[kc], s[ks], 0, 0, 0);
            }
        }

        // ---- no-max softmax: p = exp2(s_raw * comb'), masked -> 0 ----
#pragma unroll
        for (int ks = 0; ks < 4; ++ks) {
            float4 c4 = *(const float4*)(crow + kt + ks * 16 + g * 4);
            const float* cc = (const float*)&c4;
            float p0 = __builtin_amdgcn_exp2f(s[ks][0] * cc[0]);
            float p1 = __builtin_amdgcn_exp2f(s[ks][1] * cc[1]);
            float p2 = __builtin_amdgcn_exp2f(s[ks][2] * cc[2]);
            float p3 = __builtin_amdgcn_exp2f(s[ks][3] * cc[3]);
            p0 = (cc[0] < 0.f) ? 0.f : p0;
            p1 = (cc[1] < 0.f) ? 0.f : p1;
            p2 = (cc[2] < 0.f) ? 0.f : p2;
            p3 = (cc[3] < 0.f) ? 0.f : p3;
            uint2 pw;
            pw.x = cvtpk2(p0, p1);
            pw.y = cvtpk2(p2, p3);
            *(uint2*)(ptrow + ((ks * 32 + g * 8) ^ pxor)) = pw;
        }

        // ---- PV: O[q][d] += P[q][key] * V^T[d][key];  o_l += P row-sums ----
#pragma unroll
        for (int kc = 0; kc < 2; ++kc) {
            bf16x8 pf = *(const bf16x8*)(ptrow + ((kc * 64 + g * 16) ^ pxor));
            o_l = __builtin_amdgcn_mfma_f32_16x16x32_bf16(pf, vones, o_l, 0, 0, 0);
#pragma unroll
            for (int dsub = 0; dsub < 4; ++dsub) {
                bf16x8 vf = *(const bf16x8*)&Vt[cur][(dsub * 16 + qc) * 64 +
                                                     (((kc << 2) | g) ^ kxor) * 8];
                o[dsub] = __builtin_amdgcn_mfma_f32_16x16x32_bf16(pf, vf, o[dsub], 0, 0, 0);
            }
        }
        __syncthreads();  // drains DMA + protects buffer swap
        cur ^= 1;
    }

    // ---- normalize + store (attn fp32 [B,H,S,DK], concat bf16 [B,S,D]) ----
    // o_l[r] = sum_k P[q=g*4+r][k] — exactly o's row layout, no shuffles needed.
    float inv[4];
#pragma unroll
    for (int r = 0; r < 4; ++r) inv[r] = 1.0f / o_l[r];

#pragma unroll
    for (int dsub = 0; dsub < 4; ++dsub) {
#pragma unroll
        for (int r = 0; r < 4; ++r) {
            const float val = o[dsub][r] * inv[r];
            const int qg = qw + g * 4 + r;
            const int d = dsub * 16 + qc;
            attnOut[bhoff + (size_t)qg * NDK + d] = val;
            concatOut[((size_t)b_ * NS + qg) * ND + h_ * NDK + d] = f2bf(val);
        }
    }
}

// ---------------------------------------------------------------------------
extern "C" void kernel_launch(void* const* d_in, const int* in_sizes, int n_in,
                              void* d_out, int out_size, void* d_ws, size_t ws_size,
                              hipStream_t stream) {
    const float* q = (const float*)d_in[0];
    const float* k = (const float*)d_in[1];
    const float* v = (const float*)d_in[2];
    const int* am = (const int*)d_in[3];
    const float* cm = (const float*)d_in[4];
    const float* Wq = (const float*)d_in[5];
    const float* bq = (const float*)d_in[6];
    const float* Wk = (const float*)d_in[7];
    const float* bk = (const float*)d_in[8];
    const float* Wv = (const float*)d_in[9];
    const float* bv = (const float*)d_in[10];
    const float* Wo = (const float*)d_in[11];
    const float* bo = (const float*)d_in[12];

    float* out = (float*)d_out;                    // [B,S,D] fp32
    float* attn_out = out + (size_t)NB * NS * ND;  // [B,H,S,DK] fp32

    char* p = (char*)d_ws;
    float* CB = (float*)p;  p += (size_t)NS * NS * 4;
    u16* qb = (u16*)p;      p += (size_t)NB * NS * ND * 2;
    u16* kb_ = (u16*)p;     p += (size_t)NB * NS * ND * 2;
    u16* vb_ = (u16*)p;     p += (size_t)NB * NS * ND * 2;
    u16* Wqb = (u16*)p;     p += (size_t)ND * ND * 2;
    u16* Wkb = (u16*)p;     p += (size_t)ND * ND * 2;
    u16* Wvb = (u16*)p;     p += (size_t)ND * ND * 2;
    u16* Wob = (u16*)p;     p += (size_t)ND * ND * 2;
    u16* Qh = (u16*)p;      p += (size_t)NB * NS * ND * 2;
    u16* Kh = (u16*)p;      p += (size_t)NB * NS * ND * 2;
    u16* VhT = (u16*)p;     p += (size_t)NB * NS * ND * 2;
    u16* CCb = (u16*)p;     p += (size_t)NB * NS * ND * 2;

    PrepArgs pa;
    pa.qkv_s[0] = q;  pa.qkv_d[0] = qb;
    pa.qkv_s[1] = k;  pa.qkv_d[1] = kb_;
    pa.qkv_s[2] = v;  pa.qkv_d[2] = vb_;
    pa.w_s[0] = Wq;   pa.w_d[0] = Wqb;
    pa.w_s[1] = Wk;   pa.w_d[1] = Wkb;
    pa.w_s[2] = Wv;   pa.w_d[2] = Wvb;
    pa.w_s[3] = Wo;   pa.w_d[3] = Wob;
    pa.am = am;
    pa.cm = cm;
    pa.comb = CB;
    hipLaunchKernelGGL(prep_kernel, dim3(4096, 5), dim3(256), 0, stream, pa);

    MMArgs mq = {qb, Wqb, bq, (void*)Qh, 1};
    MMArgs mk = {kb_, Wkb, bk, (void*)Kh, 1};
    MMArgs mv = {vb_, Wvb, bv, (void*)VhT, 2};
    hipLaunchKernelGGL((mm_glds<128>), dim3(ND / 128, 4096 / 128, 3), dim3(256), 0, stream,
                       mq, mk, mv);

    hipLaunchKernelGGL(flash_mfma, dim3(NS / 64, NB * NH), dim3(256), 0, stream, Qh, Kh, VhT,
                       CB, attn_out, CCb);

    MMArgs mo = {CCb, Wob, bo, (void*)out, 0};
    hipLaunchKernelGGL((mm_glds<64>), dim3(ND / 64, 4096 / 128, 1), dim3(256), 0, stream,
                       mo, mo, mo);
}